// Round 18
// baseline (750.324 us; speedup 1.0000x reference)
//
#include <hip/hip_runtime.h>
#include <stdint.h>

#define LEAKY 0.1f
#define BB 8
#define NN 8192
#define SS 2048
#define KK 32
#define DD 128
#define M1 128
#define M3 256
#define FF 2048
#define H1S 136   // ushort stride for 128-col LDS rows (+8 pad -> 272B)

typedef __bf16 bf16x8 __attribute__((ext_vector_type(8)));
typedef float f32x4 __attribute__((ext_vector_type(4)));
typedef unsigned short ushort8 __attribute__((ext_vector_type(8)));

__device__ __forceinline__ unsigned short f2bf(float f){
  unsigned u = __float_as_uint(f);
  u += 0x7FFFu + ((u >> 16) & 1u);        // RTNE
  return (unsigned short)(u >> 16);
}
__device__ __forceinline__ float bf2f(unsigned short h){
  return __uint_as_float(((unsigned)h) << 16);
}
__device__ __forceinline__ float lrelu_f(float x){ return x > 0.f ? x : LEAKY * x; }

// ---------------- prep: pack xyzw (x,y,z,|p|^2 f32 rn-chain) + copy new_xyz ----------------
__global__ __launch_bounds__(256) void pc_prep(const float* __restrict__ xyz,
                                               float* __restrict__ out,
                                               float4* __restrict__ xyzw){
  int i = blockIdx.x * 256 + threadIdx.x;      // 0..65535
  int b = i >> 13, n = i & (NN - 1);
  const float* xb = xyz + (size_t)b * 3 * NN;
  float x = xb[n], y = xb[NN + n], z = xb[2 * NN + n];
  float sqn = __fadd_rn(__fadd_rn(__fmul_rn(x, x), __fmul_rn(y, y)), __fmul_rn(z, z));
  xyzw[i] = make_float4(x, y, z, sqn);
  if (n < SS) {
    out[(b * 3 + 0) * SS + n] = x;
    out[(b * 3 + 1) * SS + n] = y;
    out[(b * 3 + 2) * SS + n] = z;
  }
}

// ---------------- weight casts to bf16 ----------------
__global__ __launch_bounds__(256) void pc_cast(const float* __restrict__ w2,
                                               const float* __restrict__ w3,
                                               const float* __restrict__ wl,
                                               unsigned short* __restrict__ w2b,
                                               unsigned short* __restrict__ w3b,
                                               unsigned short* __restrict__ wlb){
  int i = blockIdx.x * 256 + threadIdx.x;      // grid covers 524288 = 256*2048 (wlin)
  if (i < M1 * DD) w2b[i] = f2bf(w2[i]);
  if (i < M3 * M1) w3b[i] = f2bf(w3[i]);
  wlb[i] = f2bf(wl[i]);
}

// ---------------- exact KNN: 4 queries per WAVE (1-wave blocks, zero barriers) ----------------
#define HB 512
#define HSH 19
#define KBASE 0xB7800000u   // sortable(2^-16); 16 bins/octave, covers d^2 in [2^-16, 2^16]
#define BCAP 128
__device__ __forceinline__ unsigned sbin(unsigned k){
  unsigned t = (k >= KBASE) ? ((k - KBASE) >> HSH) : 0u;
  return t > (HB - 1) ? (HB - 1) : t;
}
__device__ __forceinline__ unsigned knn_key(float4 p, float qx, float qy, float qz, float sqs){
  // reference op order: dot = fma(z,qz, fma(y,qy, rn(x*qx))); d = rn(rn(sqs+sqn) - rn(2*dot))
  float dt = fmaf(p.z, qz, fmaf(p.y, qy, __fmul_rn(p.x, qx)));
  float d  = __fsub_rn(__fadd_rn(sqs, p.w), __fmul_rn(2.0f, dt));
  unsigned bits = __float_as_uint(d);
  return bits ^ ((bits & 0x80000000u) ? 0xFFFFFFFFu : 0x80000000u);  // sortable
}

__global__ __launch_bounds__(64, 4) void pc_knn(const float* __restrict__ xyz,
                                                const float4* __restrict__ xyzw,
                                                int* __restrict__ knn){
  __shared__ unsigned hist[4][HB];               // 8 KB
  __shared__ unsigned long long buf[4][BCAP];    // 4 KB
  __shared__ int outidx[4][KK];                  // 0.5 KB
  const int lane = threadIdx.x;
  const unsigned long long lmlt = (1ull << lane) - 1ull;
  const int blk = blockIdx.x;                    // 0..4095
  const int b = blk >> 9;
  const int s0 = (blk & 511) * 4;
  const float* xb = xyz + (size_t)b * 3 * NN;
  float qx[4], qy[4], qz[4], sqs[4];
  #pragma unroll
  for (int q = 0; q < 4; ++q) {
    const int s = s0 + q;
    qx[q] = xb[s]; qy[q] = xb[NN + s]; qz[q] = xb[2 * NN + s];
    sqs[q] = __fadd_rn(__fadd_rn(__fmul_rn(qx[q],qx[q]), __fmul_rn(qy[q],qy[q])), __fmul_rn(qz[q],qz[q]));
  }
  const float4* pb = xyzw + (size_t)b * NN;
  #pragma unroll
  for (int h = 0; h < 4 * HB / 64; ++h) ((unsigned*)hist)[h * 64 + lane] = 0;
  // pass 1: each point loaded ONCE, 4 keys computed (wave-lockstep -> no barriers needed)
  #pragma unroll 2
  for (int i = 0; i < 128; ++i) {
    const float4 p = pb[i * 64 + lane];
    #pragma unroll
    for (int q = 0; q < 4; ++q)
      atomicAdd(&hist[q][sbin(knn_key(p, qx[q], qy[q], qz[q], sqs[q]))], 1u);
  }
  // per-query wave scan over 512 bins; lane owns bins [lane*8, lane*8+8)
  unsigned uT[4], cl[4], hT[4];
  #pragma unroll
  for (int q = 0; q < 4; ++q) {
    unsigned lb[8]; unsigned lsum = 0;
    #pragma unroll
    for (int j = 0; j < 8; ++j) { lb[j] = hist[q][lane * 8 + j]; lsum += lb[j]; }
    unsigned incl = lsum;
    #pragma unroll
    for (int off = 1; off < 64; off <<= 1) {
      unsigned v = __shfl_up(incl, off);
      if (lane >= off) incl += v;
    }
    const unsigned excl = incl - lsum;
    int myT = -1; unsigned mycl = 0;
    if (excl < KK && KK <= excl + lsum) {
      unsigned c = excl;
      #pragma unroll
      for (int j = 0; j < 8; ++j) {
        if (myT < 0) {
          if (c < KK && KK <= c + lb[j]) { myT = lane * 8 + j; mycl = c; }
          else c += lb[j];
        }
      }
    }
    unsigned long long bal = __ballot(myT >= 0);
    const int src = (int)__ffsll(bal) - 1;
    uT[q] = (unsigned)__shfl(myT, src);
    cl[q] = __shfl(mycl, src);                 // count of keys in bins < T (<= 31)
    hT[q] = hist[q][uT[q]];
  }
  // pass 2: recompute 4 keys per point; bins < T -> outidx (ordered), bin == T -> buf
  int outcnt[4] = {0,0,0,0}, bufcnt[4] = {0,0,0,0};
  #pragma unroll 2
  for (int i = 0; i < 128; ++i) {
    const float4 p = pb[i * 64 + lane];
    const int ip = i * 64 + lane;
    #pragma unroll
    for (int q = 0; q < 4; ++q) {
      const unsigned k = knn_key(p, qx[q], qy[q], qz[q], sqs[q]);
      const unsigned bin = sbin(k);
      const bool less = bin < uT[q];
      unsigned long long bl = __ballot(less);
      if (less) outidx[q][outcnt[q] + (int)__popcll(bl & lmlt)] = ip;
      outcnt[q] += (int)__popcll(bl);
      const bool eq = (bin == uT[q]);
      unsigned long long be = __ballot(eq);
      if (eq && hT[q] <= (unsigned)BCAP)
        buf[q][bufcnt[q] + (int)__popcll(be & lmlt)] =
          (((unsigned long long)k) << 32) | (unsigned)ip;
      bufcnt[q] += (int)__popcll(be);
    }
  }
  // per-query monotone (key,idx) extraction from bin T (wave-private, no barriers)
  for (int q = 0; q < 4; ++q) {
    const int need = KK - (int)cl[q];
    unsigned long long last = 0ull;
    if (hT[q] <= (unsigned)BCAP) {
      const int cnt = bufcnt[q];
      for (int t = 0; t < need; ++t) {
        unsigned long long mv = ~0ull;
        for (int j2 = lane; j2 < cnt; j2 += 64) {
          unsigned long long v = buf[q][j2];
          if (v > last && v < mv) mv = v;
        }
        #pragma unroll
        for (int off = 32; off > 0; off >>= 1) {
          unsigned long long ov = __shfl_xor(mv, off);
          if (ov < mv) mv = ov;
        }
        if (lane == 0) outidx[q][(int)cl[q] + t] = (int)(mv & 0xFFFFFFFFu);
        last = mv;
      }
    } else {
      // rare fallback: monotone extraction by rescanning global for this query
      for (int t = 0; t < need; ++t) {
        unsigned long long mv = ~0ull;
        for (int i = 0; i < 128; ++i) {
          const unsigned k = knn_key(pb[i * 64 + lane], qx[q], qy[q], qz[q], sqs[q]);
          if (sbin(k) == uT[q]) {
            unsigned long long v = (((unsigned long long)k) << 32) | (unsigned)(i * 64 + lane);
            if (v > last && v < mv) mv = v;
          }
        }
        #pragma unroll
        for (int off = 32; off > 0; off >>= 1) {
          unsigned long long ov = __shfl_xor(mv, off);
          if (ov < mv) mv = ov;
        }
        if (lane == 0) outidx[q][(int)cl[q] + t] = (int)(mv & 0xFFFFFFFFu);
        last = mv;
      }
    }
  }
  #pragma unroll
  for (int q = 0; q < 4; ++q)
    if (lane < KK) knn[(size_t)(b * SS + s0 + q) * KK + lane] = outidx[q][lane];
}

// ---------------- pc1 = points^T @ W1p^T  (fp32), [B*N][128], single pass over points ----------------
__global__ __launch_bounds__(256) void pc_pc1(const float* __restrict__ points,
                                              const float* __restrict__ w1,
                                              float* __restrict__ pc1){
  const int tx = threadIdx.x & 63, ty = threadIdx.x >> 6;
  const int m = blockIdx.x * 64 + tx;      // 0..65535
  const int b = m >> 13, n = m & (NN - 1);
  const float* pbase = points + (size_t)b * DD * NN + n;
  const float* wr = w1 + (ty * 32) * 131 + 3;   // rows [ty*32, ty*32+32)
  float acc[32];
  #pragma unroll
  for (int j = 0; j < 32; ++j) acc[j] = 0.f;
  #pragma unroll 2
  for (int c = 0; c < DD; ++c) {
    const float pv = pbase[(size_t)c * NN];
    #pragma unroll
    for (int j = 0; j < 32; ++j)
      acc[j] = fmaf(pv, wr[j * 131 + c], acc[j]);
  }
  float* dst = pc1 + (size_t)m * DD + ty * 32;
  #pragma unroll
  for (int j = 0; j < 8; ++j)
    *(float4*)(dst + j * 4) = make_float4(acc[j*4], acc[j*4+1], acc[j*4+2], acc[j*4+3]);
}

// ---------------- in-place 128x128x128 gemm (wave-private rows): hbuf = lrelu(hbuf @ W^T) ----------------
// a-frags loaded per-ks: all LDS reads precede the in-place epilogue writes within the wave.
__device__ __forceinline__ void gemm_tile_ip(unsigned short* hbuf,
                                             const unsigned short* __restrict__ wglb,
                                             int tid){
  const int lane = tid & 63;
  const int r0 = (tid >> 6) * 32;
  const int lr = lane & 15, g = lane >> 4, lkb = g * 8;
  f32x4 acc[2][8] = {};
  #pragma unroll
  for (int ks = 0; ks < 4; ++ks) {
    const int c0 = ks * 32 + lkb;
    bf16x8 a0 = __builtin_bit_cast(bf16x8, *(const ushort8*)(hbuf + (r0 + lr) * H1S + c0));
    bf16x8 a1 = __builtin_bit_cast(bf16x8, *(const ushort8*)(hbuf + (r0 + 16 + lr) * H1S + c0));
    #pragma unroll
    for (int ct = 0; ct < 8; ++ct) {
      bf16x8 bb = __builtin_bit_cast(bf16x8, *(const ushort8*)(wglb + (ct*16 + lr) * DD + c0));
      acc[0][ct] = __builtin_amdgcn_mfma_f32_16x16x32_bf16(a0, bb, acc[0][ct], 0, 0, 0);
      acc[1][ct] = __builtin_amdgcn_mfma_f32_16x16x32_bf16(a1, bb, acc[1][ct], 0, 0, 0);
    }
  }
  #pragma unroll
  for (int rt = 0; rt < 2; ++rt) {
    const int rowb = r0 + rt*16 + g * 4;
    #pragma unroll
    for (int ct = 0; ct < 8; ++ct) {
      const int o = ct*16 + lr;
      #pragma unroll
      for (int e = 0; e < 4; ++e)
        hbuf[(rowb + e) * H1S + o] = f2bf(lrelu_f(acc[rt][ct][e]));
    }
  }
}

// ---------------- gemm3 (one o-half) + in-register agg, c4-outer (low live-set) ----------------
__device__ __forceinline__ void gemm3_agg(const unsigned short* hbuf,
                                          const unsigned short* __restrict__ w3half,
                                          const float* wgtq,
                                          unsigned short* __restrict__ aggb,
                                          int lane, int r0, int rowbase_q, int oh){
  const int lr = lane & 15, g = lane >> 4;
  #pragma unroll
  for (int ch = 0; ch < 2; ++ch) {
    f32x4 acc[2][4] = {};
    #pragma unroll
    for (int ks = 0; ks < 4; ++ks) {
      const int c0 = ks * 32 + g * 8;
      bf16x8 a0 = __builtin_bit_cast(bf16x8, *(const ushort8*)(hbuf + (r0 + lr) * H1S + c0));
      bf16x8 a1 = __builtin_bit_cast(bf16x8, *(const ushort8*)(hbuf + (r0 + 16 + lr) * H1S + c0));
      #pragma unroll
      for (int c4 = 0; c4 < 4; ++c4) {
        const int ct = ch * 4 + c4;
        bf16x8 bb = __builtin_bit_cast(bf16x8, *(const ushort8*)(w3half + (ct*16 + lr) * DD + c0));
        acc[0][c4] = __builtin_amdgcn_mfma_f32_16x16x32_bf16(a0, bb, acc[0][c4], 0, 0, 0);
        acc[1][c4] = __builtin_amdgcn_mfma_f32_16x16x32_bf16(a1, bb, acc[1][c4], 0, 0, 0);
      }
    }
    #pragma unroll
    for (int c4 = 0; c4 < 4; ++c4) {
      float accw[8] = {};
      #pragma unroll
      for (int rt = 0; rt < 2; ++rt) {
        #pragma unroll
        for (int e = 0; e < 4; ++e) {
          const float4* wr = (const float4*)(wgtq + (rt*16 + g*4 + e) * 8);
          const float4 wa = wr[0], wb = wr[1];
          const float h = lrelu_f(acc[rt][c4][e]);   // layer-3 activation
          accw[0] = fmaf(h, wa.x, accw[0]);
          accw[1] = fmaf(h, wa.y, accw[1]);
          accw[2] = fmaf(h, wa.z, accw[2]);
          accw[3] = fmaf(h, wa.w, accw[3]);
          accw[4] = fmaf(h, wb.x, accw[4]);
          accw[5] = fmaf(h, wb.y, accw[5]);
          accw[6] = fmaf(h, wb.z, accw[6]);
          accw[7] = fmaf(h, wb.w, accw[7]);
        }
      }
      #pragma unroll
      for (int w = 0; w < 8; ++w) {
        float v = accw[w];
        v += __shfl_xor(v, 16);
        v += __shfl_xor(v, 32);
        accw[w] = v;
      }
      if (g == 0) {
        const int o = (ch * 4 + c4) * 16 + lr;
        ushort8 pk;
        #pragma unroll
        for (int w = 0; w < 8; ++w) pk[w] = f2bf(accw[w]);
        *(ushort8*)(aggb + (size_t)rowbase_q * FF + oh * (M1 * 8) + o * 8) = pk;
      }
    }
  }
}

// ---------------- fused main: 4 queries, 256 thr, wave-private chain, 1 barrier ----------------
__global__ __launch_bounds__(256, 3) void pc_main(const float* __restrict__ xyz,
    const int* __restrict__ knn, const float* __restrict__ pc1,
    const float* __restrict__ w1,
    const unsigned short* __restrict__ w2b, const unsigned short* __restrict__ w3b,
    const float* __restrict__ wn_w1, const float* __restrict__ wn_b1,
    const float* __restrict__ wn_w2, const float* __restrict__ wn_b2,
    const float* __restrict__ wn_w3, const float* __restrict__ wn_b3,
    unsigned short* __restrict__ aggb){
  __shared__ __align__(16) unsigned short hbuf[128 * H1S];   // 34816 B
  __shared__ __align__(16) float wgtF[4 * 32 * 8];           // 4096 B
  __shared__ float w1d[M1 * 3];                              // 1536 B  -> 40448 B total
  const int tid = threadIdx.x;
  const int wave = tid >> 6, lane = tid & 63;
  const int blk = blockIdx.x;          // 0..4095
  const int b = blk >> 9;
  const int s0 = (blk & 511) * 4;
  const float* xb = xyz + (size_t)b * 3 * NN;
  if (tid < M1) {
    w1d[tid*3+0] = w1[tid*131+0];
    w1d[tid*3+1] = w1[tid*131+1];
    w1d[tid*3+2] = w1[tid*131+2];
  }
  // wave-private: wave = query q; 2 threads per neighbor row
  const int q = wave, k = lane & 31, t2 = lane >> 5;
  const int s = s0 + q;
  const int j = knn[(size_t)(b * SS + s) * KK + k];
  const float dx = xb[j] - xb[s];
  const float dy = xb[NN + j] - xb[NN + s];
  const float dz = xb[2*NN + j] - xb[2*NN + s];
  if (t2 == 0) {
    // weight-net for row k -> wgtF[q][k][0..7] (f32)
    float t0[8], t1[8], t2v[8];
    #pragma unroll
    for (int o = 0; o < 8; ++o)
      t0[o] = fmaxf(fmaf(dz, wn_w1[o*3+2], fmaf(dy, wn_w1[o*3+1], fmaf(dx, wn_w1[o*3+0], wn_b1[o]))), 0.f);
    #pragma unroll
    for (int o = 0; o < 8; ++o) {
      float a = wn_b2[o];
      #pragma unroll
      for (int i2 = 0; i2 < 8; ++i2) a = fmaf(t0[i2], wn_w2[o*8+i2], a);
      t1[o] = fmaxf(a, 0.f);
    }
    #pragma unroll
    for (int o = 0; o < 8; ++o) {
      float a = wn_b3[o];
      #pragma unroll
      for (int i2 = 0; i2 < 8; ++i2) a = fmaf(t1[i2], wn_w3[o*8+i2], a);
      t2v[o] = fmaxf(a, 0.f);
    }
    float* wdst = wgtF + (q * 32 + k) * 8;
    *(float4*)(wdst + 0) = make_float4(t2v[0], t2v[1], t2v[2], t2v[3]);
    *(float4*)(wdst + 4) = make_float4(t2v[4], t2v[5], t2v[6], t2v[7]);
  }
  __syncthreads();   // w1d ready (wgtF/hbuf deps are intra-wave from here on)
  // h1: row q*32+k, cols t2*64..t2*64+63 (16 float4 gather per thread)
  {
    const float4* pcrow = (const float4*)(pc1 + (size_t)(b * NN + j) * DD) + t2 * 16;
    unsigned short* hrow = hbuf + (q * 32 + k) * H1S + t2 * 64;
    #pragma unroll
    for (int o8 = 0; o8 < 8; ++o8) {
      float4 p0 = pcrow[o8*2], p1 = pcrow[o8*2+1];
      float vv[8] = {p0.x, p0.y, p0.z, p0.w, p1.x, p1.y, p1.z, p1.w};
      ushort8 pk;
      #pragma unroll
      for (int e = 0; e < 8; ++e) {
        const int o = t2*64 + o8*8 + e;
        float v = vv[e] + fmaf(dz, w1d[o*3+2], fmaf(dy, w1d[o*3+1], __fmul_rn(dx, w1d[o*3+0])));
        pk[e] = f2bf(lrelu_f(v));
      }
      *(ushort8*)(hrow + o8*8) = pk;
    }
  }
  // no barrier: rows 32q..32q+31 are written and read only by this wave
  gemm_tile_ip(hbuf, w2b, tid);                   // layer 2 (in-place)
  const int rowbase_q = b * SS + s0 + q;
  const float* wgtq = wgtF + q * 256;
  gemm3_agg(hbuf, w3b,            wgtq, aggb, lane, wave * 32, rowbase_q, 0);
  gemm3_agg(hbuf, w3b + 128 * DD, wgtq, aggb, lane, wave * 32, rowbase_q, 1);
}

// ---------------- final: out[b][o][s] = lrelu(agg[bs][:] . wlin[o][:]) ----------------
#define FSTR 72
__global__ __launch_bounds__(256) void pc_final(const unsigned short* __restrict__ aggb,
                                                const unsigned short* __restrict__ wlb,
                                                float* __restrict__ outp){
  __shared__ __align__(16) unsigned short At[128 * FSTR];
  __shared__ __align__(16) unsigned short Bt[128 * FSTR];
  const int tid = threadIdx.x;
  const int mb = blockIdx.x;      // 0..127
  const int nb = blockIdx.y;      // 0..1
  const int lane = tid & 63, wv = tid >> 6;
  const int wm = (wv & 1) * 64, wn = (wv >> 1) * 64;
  const int lr = lane & 15, lkb = (lane >> 4) * 8;
  f32x4 acc[4][4] = {};
  for (int kt = 0; kt < FF / 64; ++kt) {
    #pragma unroll
    for (int it = 0; it < 4; ++it) {
      int seg = it * 256 + tid;
      int row = seg >> 3, c16 = seg & 7;
      *(ushort8*)(At + row * FSTR + c16 * 8) =
        *(const ushort8*)(aggb + (size_t)(mb * 128 + row) * FF + kt * 64 + c16 * 8);
      *(ushort8*)(Bt + row * FSTR + c16 * 8) =
        *(const ushort8*)(wlb + (size_t)(nb * 128 + row) * FF + kt * 64 + c16 * 8);
    }
    __syncthreads();
    #pragma unroll
    for (int ks = 0; ks < 2; ++ks) {
      const int c0 = ks * 32 + lkb;
      bf16x8 a[4], bb[4];
      #pragma unroll
      for (int rt = 0; rt < 4; ++rt)
        a[rt] = __builtin_bit_cast(bf16x8, *(const ushort8*)(At + (wm + rt*16 + lr) * FSTR + c0));
      #pragma unroll
      for (int ct = 0; ct < 4; ++ct)
        bb[ct] = __builtin_bit_cast(bf16x8, *(const ushort8*)(Bt + (wn + ct*16 + lr) * FSTR + c0));
      #pragma unroll
      for (int rt = 0; rt < 4; ++rt)
        #pragma unroll
        for (int ct = 0; ct < 4; ++ct)
          acc[rt][ct] = __builtin_amdgcn_mfma_f32_16x16x32_bf16(a[rt], bb[ct], acc[rt][ct], 0,0,0);
    }
    __syncthreads();
  }
  #pragma unroll
  for (int rt = 0; rt < 4; ++rt) {
    const int r0 = mb * 128 + wm + rt * 16 + (lane >> 4) * 4;
    const int bq = r0 >> 11;
    const int sq = r0 & (SS - 1);
    #pragma unroll
    for (int ct = 0; ct < 4; ++ct) {
      const int o = nb * 128 + wn + ct * 16 + lr;
      float4 vvv = make_float4(lrelu_f(acc[rt][ct][0]), lrelu_f(acc[rt][ct][1]),
                               lrelu_f(acc[rt][ct][2]), lrelu_f(acc[rt][ct][3]));
      *(float4*)(outp + (size_t)bq * M3 * SS + (size_t)o * SS + sq) = vvv;
    }
  }
}

extern "C" void kernel_launch(void* const* d_in, const int* in_sizes, int n_in,
                              void* d_out, int out_size, void* d_ws, size_t ws_size,
                              hipStream_t stream) {
  const float* xyz    = (const float*)d_in[0];
  const float* points = (const float*)d_in[1];
  const float* w1     = (const float*)d_in[2];
  const float* w2     = (const float*)d_in[3];
  const float* w3     = (const float*)d_in[4];
  const float* wn_w1  = (const float*)d_in[5];
  const float* wn_b1  = (const float*)d_in[6];
  const float* wn_w2  = (const float*)d_in[7];
  const float* wn_b2  = (const float*)d_in[8];
  const float* wn_w3  = (const float*)d_in[9];
  const float* wn_b3  = (const float*)d_in[10];
  const float* wlin   = (const float*)d_in[11];
  float* out = (float*)d_out;
  char* ws = (char*)d_ws;
  // ws layout (needs ~102 MB)
  int*            knn  = (int*)(ws + 0);                                  // 2 MB
  float4*         xyzw = (float4*)(ws + (2ull  << 20));                   // 1 MB
  float*          pc1  = (float*)(ws + (3ull  << 20));                    // 32 MB
  unsigned short* w2b  = (unsigned short*)(ws + (35ull << 20));           // 32 KB
  unsigned short* w3b  = (unsigned short*)(ws + (35ull << 20) + (1ull << 16)); // 64 KB
  unsigned short* wlb  = (unsigned short*)(ws + (36ull << 20));           // 1 MB
  unsigned short* aggb = (unsigned short*)(ws + (38ull << 20));           // 64 MB

  hipLaunchKernelGGL(pc_prep, dim3(256), dim3(256), 0, stream, xyz, out, xyzw);
  hipLaunchKernelGGL(pc_cast, dim3(2048), dim3(256), 0, stream, w2, w3, wlin, w2b, w3b, wlb);
  hipLaunchKernelGGL(pc_knn, dim3(4096), dim3(64), 0, stream, xyz, (const float4*)xyzw, knn);
  hipLaunchKernelGGL(pc_pc1, dim3(1024), dim3(256), 0, stream, points, w1, pc1);
  hipLaunchKernelGGL(pc_main, dim3(4096), dim3(256), 0, stream, xyz, knn, pc1, w1,
                     w2b, w3b, wn_w1, wn_b1, wn_w2, wn_b2, wn_w3, wn_b3, aggb);
  hipLaunchKernelGGL(pc_final, dim3(128, 2), dim3(256), 0, stream, aggb, wlb, out + (BB * 3 * SS));
}

// Round 19
// 670.348 us; speedup vs baseline: 1.1193x; 1.1193x over previous
//
#include <hip/hip_runtime.h>
#include <stdint.h>

#define LEAKY 0.1f
#define BB 8
#define NN 8192
#define SS 2048
#define KK 32
#define DD 128
#define M1 128
#define M3 256
#define FF 2048
#define H1S 136   // ushort stride for 128-col LDS rows (+8 pad -> 272B)

typedef __bf16 bf16x8 __attribute__((ext_vector_type(8)));
typedef float f32x4 __attribute__((ext_vector_type(4)));
typedef unsigned short ushort8 __attribute__((ext_vector_type(8)));

__device__ __forceinline__ unsigned short f2bf(float f){
  unsigned u = __float_as_uint(f);
  u += 0x7FFFu + ((u >> 16) & 1u);        // RTNE
  return (unsigned short)(u >> 16);
}
__device__ __forceinline__ float bf2f(unsigned short h){
  return __uint_as_float(((unsigned)h) << 16);
}
__device__ __forceinline__ float lrelu_f(float x){ return x > 0.f ? x : LEAKY * x; }

// ---------------- prep: pack xyzw (x,y,z,|p|^2 f32 rn-chain) + copy new_xyz ----------------
__global__ __launch_bounds__(256) void pc_prep(const float* __restrict__ xyz,
                                               float* __restrict__ out,
                                               float4* __restrict__ xyzw){
  int i = blockIdx.x * 256 + threadIdx.x;      // 0..65535
  int b = i >> 13, n = i & (NN - 1);
  const float* xb = xyz + (size_t)b * 3 * NN;
  float x = xb[n], y = xb[NN + n], z = xb[2 * NN + n];
  float sqn = __fadd_rn(__fadd_rn(__fmul_rn(x, x), __fmul_rn(y, y)), __fmul_rn(z, z));
  xyzw[i] = make_float4(x, y, z, sqn);
  if (n < SS) {
    out[(b * 3 + 0) * SS + n] = x;
    out[(b * 3 + 1) * SS + n] = y;
    out[(b * 3 + 2) * SS + n] = z;
  }
}

// ---------------- weight casts to bf16 ----------------
__global__ __launch_bounds__(256) void pc_cast(const float* __restrict__ w2,
                                               const float* __restrict__ w3,
                                               const float* __restrict__ wl,
                                               unsigned short* __restrict__ w2b,
                                               unsigned short* __restrict__ w3b,
                                               unsigned short* __restrict__ wlb){
  int i = blockIdx.x * 256 + threadIdx.x;      // grid covers 524288 = 256*2048 (wlin)
  if (i < M1 * DD) w2b[i] = f2bf(w2[i]);
  if (i < M3 * M1) w3b[i] = f2bf(w3[i]);
  wlb[i] = f2bf(wl[i]);
}

// ---------------- exact KNN: 4 queries/block (wave=query), deep-unrolled scans ----------------
#define HB 512
#define HSH 19
#define KBASE 0xB7800000u   // sortable(2^-16); 16 bins/octave, covers d^2 in [2^-16, 2^16]
#define BCAP 128
__device__ __forceinline__ unsigned sbin(unsigned k){
  unsigned t = (k >= KBASE) ? ((k - KBASE) >> HSH) : 0u;
  return t > (HB - 1) ? (HB - 1) : t;
}
__device__ __forceinline__ unsigned knn_key(float4 p, float qx, float qy, float qz, float sqs){
  // reference op order: dot = fma(z,qz, fma(y,qy, rn(x*qx))); d = rn(rn(sqs+sqn) - rn(2*dot))
  float dt = fmaf(p.z, qz, fmaf(p.y, qy, __fmul_rn(p.x, qx)));
  float d  = __fsub_rn(__fadd_rn(sqs, p.w), __fmul_rn(2.0f, dt));
  unsigned bits = __float_as_uint(d);
  return bits ^ ((bits & 0x80000000u) ? 0xFFFFFFFFu : 0x80000000u);  // sortable
}

__global__ __launch_bounds__(256, 4) void pc_knn(const float* __restrict__ xyz,
                                                 const float4* __restrict__ xyzw,
                                                 int* __restrict__ knn){
  __shared__ unsigned hist[4][HB];               // 8 KB (wave-private slices)
  __shared__ unsigned long long buf[4][BCAP];    // 4 KB
  __shared__ int outidx[4][KK];                  // 0.5 KB
  const int tid = threadIdx.x;
  const int wave = tid >> 6, lane = tid & 63;
  const int qid = blockIdx.x * 4 + wave;         // grid 4096
  const int b = qid >> 11, s = qid & (SS - 1);
  const unsigned long long lmlt = (1ull << lane) - 1ull;
  const float* xb = xyz + (size_t)b * 3 * NN;
  const float qx = xb[s], qy = xb[NN + s], qz = xb[2 * NN + s];
  const float sqs = __fadd_rn(__fadd_rn(__fmul_rn(qx,qx), __fmul_rn(qy,qy)), __fmul_rn(qz,qz));
  const float4* pb = xyzw + (size_t)b * NN;
  #pragma unroll
  for (int h = 0; h < HB / 64; ++h) hist[wave][h * 64 + lane] = 0;
  __syncthreads();
  // pass 1: histogram; unroll 8 keeps 8 independent loads in flight (latency hiding)
  #pragma unroll 8
  for (int i = 0; i < 128; ++i)
    atomicAdd(&hist[wave][sbin(knn_key(pb[i * 64 + lane], qx, qy, qz, sqs))], 1u);
  __syncthreads();
  // wave scan over own 512 bins; lane owns bins [lane*8, lane*8+8)
  unsigned lb[8]; unsigned lsum = 0;
  #pragma unroll
  for (int j = 0; j < 8; ++j) { lb[j] = hist[wave][lane * 8 + j]; lsum += lb[j]; }
  unsigned incl = lsum;
  #pragma unroll
  for (int off = 1; off < 64; off <<= 1) {
    unsigned v = __shfl_up(incl, off);
    if (lane >= off) incl += v;
  }
  const unsigned excl = incl - lsum;
  int myT = -1; unsigned mycl = 0;
  if (excl < KK && KK <= excl + lsum) {
    unsigned c = excl;
    #pragma unroll
    for (int j = 0; j < 8; ++j) {
      if (myT < 0) {
        if (c < KK && KK <= c + lb[j]) { myT = lane * 8 + j; mycl = c; }
        else c += lb[j];
      }
    }
  }
  unsigned long long bal = __ballot(myT >= 0);
  const int src = (int)__ffsll(bal) - 1;
  const unsigned uT = (unsigned)__shfl(myT, src);
  const unsigned cl = __shfl(mycl, src);      // count of keys in bins < T (<= 31)
  const unsigned hT = hist[wave][uT];
  const bool useBuf = (hT <= (unsigned)BCAP);
  // pass 2: recompute keys (unroll 8); bins < T -> outidx (ordered), bin == T -> buf
  int outcnt = 0, bufcnt = 0;
  #pragma unroll 8
  for (int i = 0; i < 128; ++i) {
    const unsigned k = knn_key(pb[i * 64 + lane], qx, qy, qz, sqs);
    const unsigned bin = sbin(k);
    const bool less = bin < uT;
    unsigned long long bl = __ballot(less);
    if (less) outidx[wave][outcnt + (int)__popcll(bl & lmlt)] = i * 64 + lane;
    outcnt += (int)__popcll(bl);
    const bool eq = (bin == uT);
    unsigned long long be = __ballot(eq);
    if (useBuf && eq)
      buf[wave][bufcnt + (int)__popcll(be & lmlt)] =
        (((unsigned long long)k) << 32) | (unsigned)(i * 64 + lane);
    bufcnt += (int)__popcll(be);
  }
  const int need = KK - (int)cl;
  if (useBuf) {
    // monotone (key,idx) extraction: buf never modified -> wave-private, no barriers
    unsigned long long last = 0ull;
    for (int t = 0; t < need; ++t) {
      unsigned long long mv = ~0ull;
      for (int j2 = lane; j2 < bufcnt; j2 += 64) {
        unsigned long long v = buf[wave][j2];
        if (v > last && v < mv) mv = v;
      }
      #pragma unroll
      for (int off = 32; off > 0; off >>= 1) {
        unsigned long long ov = __shfl_xor(mv, off);
        if (ov < mv) mv = ov;
      }
      if (lane == 0) outidx[wave][(int)cl + t] = (int)(mv & 0xFFFFFFFFu);
      last = mv;
    }
  } else {
    // rare fallback: monotone extraction by rescanning global
    unsigned long long last = 0ull;
    for (int t = 0; t < need; ++t) {
      unsigned long long mv = ~0ull;
      for (int i = 0; i < 128; ++i) {
        const unsigned k = knn_key(pb[i * 64 + lane], qx, qy, qz, sqs);
        if (sbin(k) == uT) {
          unsigned long long v = (((unsigned long long)k) << 32) | (unsigned)(i * 64 + lane);
          if (v > last && v < mv) mv = v;
        }
      }
      #pragma unroll
      for (int off = 32; off > 0; off >>= 1) {
        unsigned long long ov = __shfl_xor(mv, off);
        if (ov < mv) mv = ov;
      }
      if (lane == 0) outidx[wave][(int)cl + t] = (int)(mv & 0xFFFFFFFFu);
      last = mv;
    }
  }
  __threadfence_block();
  if (lane < KK) knn[(size_t)qid * KK + lane] = outidx[wave][lane];
}

// ---------------- pc1 = points^T @ W1p^T  (fp32), [B*N][128], single pass over points ----------------
__global__ __launch_bounds__(256) void pc_pc1(const float* __restrict__ points,
                                              const float* __restrict__ w1,
                                              float* __restrict__ pc1){
  const int tx = threadIdx.x & 63, ty = threadIdx.x >> 6;
  const int m = blockIdx.x * 64 + tx;      // 0..65535
  const int b = m >> 13, n = m & (NN - 1);
  const float* pbase = points + (size_t)b * DD * NN + n;
  const float* wr = w1 + (ty * 32) * 131 + 3;   // rows [ty*32, ty*32+32)
  float acc[32];
  #pragma unroll
  for (int j = 0; j < 32; ++j) acc[j] = 0.f;
  #pragma unroll 2
  for (int c = 0; c < DD; ++c) {
    const float pv = pbase[(size_t)c * NN];
    #pragma unroll
    for (int j = 0; j < 32; ++j)
      acc[j] = fmaf(pv, wr[j * 131 + c], acc[j]);
  }
  float* dst = pc1 + (size_t)m * DD + ty * 32;
  #pragma unroll
  for (int j = 0; j < 8; ++j)
    *(float4*)(dst + j * 4) = make_float4(acc[j*4], acc[j*4+1], acc[j*4+2], acc[j*4+3]);
}

// ---------------- in-place 128x128x128 gemm (wave-private rows): hbuf = lrelu(hbuf @ W^T) ----------------
// a-frags loaded per-ks: all LDS reads precede the in-place epilogue writes within the wave.
__device__ __forceinline__ void gemm_tile_ip(unsigned short* hbuf,
                                             const unsigned short* __restrict__ wglb,
                                             int tid){
  const int lane = tid & 63;
  const int r0 = (tid >> 6) * 32;
  const int lr = lane & 15, g = lane >> 4, lkb = g * 8;
  f32x4 acc[2][8] = {};
  #pragma unroll
  for (int ks = 0; ks < 4; ++ks) {
    const int c0 = ks * 32 + lkb;
    bf16x8 a0 = __builtin_bit_cast(bf16x8, *(const ushort8*)(hbuf + (r0 + lr) * H1S + c0));
    bf16x8 a1 = __builtin_bit_cast(bf16x8, *(const ushort8*)(hbuf + (r0 + 16 + lr) * H1S + c0));
    #pragma unroll
    for (int ct = 0; ct < 8; ++ct) {
      bf16x8 bb = __builtin_bit_cast(bf16x8, *(const ushort8*)(wglb + (ct*16 + lr) * DD + c0));
      acc[0][ct] = __builtin_amdgcn_mfma_f32_16x16x32_bf16(a0, bb, acc[0][ct], 0, 0, 0);
      acc[1][ct] = __builtin_amdgcn_mfma_f32_16x16x32_bf16(a1, bb, acc[1][ct], 0, 0, 0);
    }
  }
  #pragma unroll
  for (int rt = 0; rt < 2; ++rt) {
    const int rowb = r0 + rt*16 + g * 4;
    #pragma unroll
    for (int ct = 0; ct < 8; ++ct) {
      const int o = ct*16 + lr;
      #pragma unroll
      for (int e = 0; e < 4; ++e)
        hbuf[(rowb + e) * H1S + o] = f2bf(lrelu_f(acc[rt][ct][e]));
    }
  }
}

// ---------------- gemm3 (one o-half) + in-register agg, c4-outer (low live-set) ----------------
__device__ __forceinline__ void gemm3_agg(const unsigned short* hbuf,
                                          const unsigned short* __restrict__ w3half,
                                          const float* wgtq,
                                          unsigned short* __restrict__ aggb,
                                          int lane, int r0, int rowbase_q, int oh){
  const int lr = lane & 15, g = lane >> 4;
  #pragma unroll
  for (int ch = 0; ch < 2; ++ch) {
    f32x4 acc[2][4] = {};
    #pragma unroll
    for (int ks = 0; ks < 4; ++ks) {
      const int c0 = ks * 32 + g * 8;
      bf16x8 a0 = __builtin_bit_cast(bf16x8, *(const ushort8*)(hbuf + (r0 + lr) * H1S + c0));
      bf16x8 a1 = __builtin_bit_cast(bf16x8, *(const ushort8*)(hbuf + (r0 + 16 + lr) * H1S + c0));
      #pragma unroll
      for (int c4 = 0; c4 < 4; ++c4) {
        const int ct = ch * 4 + c4;
        bf16x8 bb = __builtin_bit_cast(bf16x8, *(const ushort8*)(w3half + (ct*16 + lr) * DD + c0));
        acc[0][c4] = __builtin_amdgcn_mfma_f32_16x16x32_bf16(a0, bb, acc[0][c4], 0, 0, 0);
        acc[1][c4] = __builtin_amdgcn_mfma_f32_16x16x32_bf16(a1, bb, acc[1][c4], 0, 0, 0);
      }
    }
    #pragma unroll
    for (int c4 = 0; c4 < 4; ++c4) {
      float accw[8] = {};
      #pragma unroll
      for (int rt = 0; rt < 2; ++rt) {
        #pragma unroll
        for (int e = 0; e < 4; ++e) {
          const float4* wr = (const float4*)(wgtq + (rt*16 + g*4 + e) * 8);
          const float4 wa = wr[0], wb = wr[1];
          const float h = lrelu_f(acc[rt][c4][e]);   // layer-3 activation
          accw[0] = fmaf(h, wa.x, accw[0]);
          accw[1] = fmaf(h, wa.y, accw[1]);
          accw[2] = fmaf(h, wa.z, accw[2]);
          accw[3] = fmaf(h, wa.w, accw[3]);
          accw[4] = fmaf(h, wb.x, accw[4]);
          accw[5] = fmaf(h, wb.y, accw[5]);
          accw[6] = fmaf(h, wb.z, accw[6]);
          accw[7] = fmaf(h, wb.w, accw[7]);
        }
      }
      #pragma unroll
      for (int w = 0; w < 8; ++w) {
        float v = accw[w];
        v += __shfl_xor(v, 16);
        v += __shfl_xor(v, 32);
        accw[w] = v;
      }
      if (g == 0) {
        const int o = (ch * 4 + c4) * 16 + lr;
        ushort8 pk;
        #pragma unroll
        for (int w = 0; w < 8; ++w) pk[w] = f2bf(accw[w]);
        *(ushort8*)(aggb + (size_t)rowbase_q * FF + oh * (M1 * 8) + o * 8) = pk;
      }
    }
  }
}

// ---------------- fused main: 4 queries, 256 thr, wave-private chain, 1 barrier ----------------
__global__ __launch_bounds__(256, 3) void pc_main(const float* __restrict__ xyz,
    const int* __restrict__ knn, const float* __restrict__ pc1,
    const float* __restrict__ w1,
    const unsigned short* __restrict__ w2b, const unsigned short* __restrict__ w3b,
    const float* __restrict__ wn_w1, const float* __restrict__ wn_b1,
    const float* __restrict__ wn_w2, const float* __restrict__ wn_b2,
    const float* __restrict__ wn_w3, const float* __restrict__ wn_b3,
    unsigned short* __restrict__ aggb){
  __shared__ __align__(16) unsigned short hbuf[128 * H1S];   // 34816 B
  __shared__ __align__(16) float wgtF[4 * 32 * 8];           // 4096 B
  __shared__ float w1d[M1 * 3];                              // 1536 B  -> 40448 B total
  const int tid = threadIdx.x;
  const int wave = tid >> 6, lane = tid & 63;
  const int blk = blockIdx.x;          // 0..4095
  const int b = blk >> 9;
  const int s0 = (blk & 511) * 4;
  const float* xb = xyz + (size_t)b * 3 * NN;
  if (tid < M1) {
    w1d[tid*3+0] = w1[tid*131+0];
    w1d[tid*3+1] = w1[tid*131+1];
    w1d[tid*3+2] = w1[tid*131+2];
  }
  // wave-private: wave = query q; 2 threads per neighbor row
  const int q = wave, k = lane & 31, t2 = lane >> 5;
  const int s = s0 + q;
  const int j = knn[(size_t)(b * SS + s) * KK + k];
  const float dx = xb[j] - xb[s];
  const float dy = xb[NN + j] - xb[NN + s];
  const float dz = xb[2*NN + j] - xb[2*NN + s];
  if (t2 == 0) {
    // weight-net for row k -> wgtF[q][k][0..7] (f32)
    float t0[8], t1[8], t2v[8];
    #pragma unroll
    for (int o = 0; o < 8; ++o)
      t0[o] = fmaxf(fmaf(dz, wn_w1[o*3+2], fmaf(dy, wn_w1[o*3+1], fmaf(dx, wn_w1[o*3+0], wn_b1[o]))), 0.f);
    #pragma unroll
    for (int o = 0; o < 8; ++o) {
      float a = wn_b2[o];
      #pragma unroll
      for (int i2 = 0; i2 < 8; ++i2) a = fmaf(t0[i2], wn_w2[o*8+i2], a);
      t1[o] = fmaxf(a, 0.f);
    }
    #pragma unroll
    for (int o = 0; o < 8; ++o) {
      float a = wn_b3[o];
      #pragma unroll
      for (int i2 = 0; i2 < 8; ++i2) a = fmaf(t1[i2], wn_w3[o*8+i2], a);
      t2v[o] = fmaxf(a, 0.f);
    }
    float* wdst = wgtF + (q * 32 + k) * 8;
    *(float4*)(wdst + 0) = make_float4(t2v[0], t2v[1], t2v[2], t2v[3]);
    *(float4*)(wdst + 4) = make_float4(t2v[4], t2v[5], t2v[6], t2v[7]);
  }
  __syncthreads();   // w1d ready (wgtF/hbuf deps are intra-wave from here on)
  // h1: row q*32+k, cols t2*64..t2*64+63 (16 float4 gather per thread)
  {
    const float4* pcrow = (const float4*)(pc1 + (size_t)(b * NN + j) * DD) + t2 * 16;
    unsigned short* hrow = hbuf + (q * 32 + k) * H1S + t2 * 64;
    #pragma unroll
    for (int o8 = 0; o8 < 8; ++o8) {
      float4 p0 = pcrow[o8*2], p1 = pcrow[o8*2+1];
      float vv[8] = {p0.x, p0.y, p0.z, p0.w, p1.x, p1.y, p1.z, p1.w};
      ushort8 pk;
      #pragma unroll
      for (int e = 0; e < 8; ++e) {
        const int o = t2*64 + o8*8 + e;
        float v = vv[e] + fmaf(dz, w1d[o*3+2], fmaf(dy, w1d[o*3+1], __fmul_rn(dx, w1d[o*3+0])));
        pk[e] = f2bf(lrelu_f(v));
      }
      *(ushort8*)(hrow + o8*8) = pk;
    }
  }
  // no barrier: rows 32q..32q+31 are written and read only by this wave
  gemm_tile_ip(hbuf, w2b, tid);                   // layer 2 (in-place)
  const int rowbase_q = b * SS + s0 + q;
  const float* wgtq = wgtF + q * 256;
  gemm3_agg(hbuf, w3b,            wgtq, aggb, lane, wave * 32, rowbase_q, 0);
  gemm3_agg(hbuf, w3b + 128 * DD, wgtq, aggb, lane, wave * 32, rowbase_q, 1);
}

// ---------------- final: out[b][o][s] = lrelu(agg[bs][:] . wlin[o][:]) ----------------
#define FSTR 72
__global__ __launch_bounds__(256) void pc_final(const unsigned short* __restrict__ aggb,
                                                const unsigned short* __restrict__ wlb,
                                                float* __restrict__ outp){
  __shared__ __align__(16) unsigned short At[128 * FSTR];
  __shared__ __align__(16) unsigned short Bt[128 * FSTR];
  const int tid = threadIdx.x;
  const int mb = blockIdx.x;      // 0..127
  const int nb = blockIdx.y;      // 0..1
  const int lane = tid & 63, wv = tid >> 6;
  const int wm = (wv & 1) * 64, wn = (wv >> 1) * 64;
  const int lr = lane & 15, lkb = (lane >> 4) * 8;
  f32x4 acc[4][4] = {};
  for (int kt = 0; kt < FF / 64; ++kt) {
    #pragma unroll
    for (int it = 0; it < 4; ++it) {
      int seg = it * 256 + tid;
      int row = seg >> 3, c16 = seg & 7;
      *(ushort8*)(At + row * FSTR + c16 * 8) =
        *(const ushort8*)(aggb + (size_t)(mb * 128 + row) * FF + kt * 64 + c16 * 8);
      *(ushort8*)(Bt + row * FSTR + c16 * 8) =
        *(const ushort8*)(wlb + (size_t)(nb * 128 + row) * FF + kt * 64 + c16 * 8);
    }
    __syncthreads();
    #pragma unroll
    for (int ks = 0; ks < 2; ++ks) {
      const int c0 = ks * 32 + lkb;
      bf16x8 a[4], bb[4];
      #pragma unroll
      for (int rt = 0; rt < 4; ++rt)
        a[rt] = __builtin_bit_cast(bf16x8, *(const ushort8*)(At + (wm + rt*16 + lr) * FSTR + c0));
      #pragma unroll
      for (int ct = 0; ct < 4; ++ct)
        bb[ct] = __builtin_bit_cast(bf16x8, *(const ushort8*)(Bt + (wn + ct*16 + lr) * FSTR + c0));
      #pragma unroll
      for (int rt = 0; rt < 4; ++rt)
        #pragma unroll
        for (int ct = 0; ct < 4; ++ct)
          acc[rt][ct] = __builtin_amdgcn_mfma_f32_16x16x32_bf16(a[rt], bb[ct], acc[rt][ct], 0,0,0);
    }
    __syncthreads();
  }
  #pragma unroll
  for (int rt = 0; rt < 4; ++rt) {
    const int r0 = mb * 128 + wm + rt * 16 + (lane >> 4) * 4;
    const int bq = r0 >> 11;
    const int sq = r0 & (SS - 1);
    #pragma unroll
    for (int ct = 0; ct < 4; ++ct) {
      const int o = nb * 128 + wn + ct * 16 + lr;
      float4 vvv = make_float4(lrelu_f(acc[rt][ct][0]), lrelu_f(acc[rt][ct][1]),
                               lrelu_f(acc[rt][ct][2]), lrelu_f(acc[rt][ct][3]));
      *(float4*)(outp + (size_t)bq * M3 * SS + (size_t)o * SS + sq) = vvv;
    }
  }
}

extern "C" void kernel_launch(void* const* d_in, const int* in_sizes, int n_in,
                              void* d_out, int out_size, void* d_ws, size_t ws_size,
                              hipStream_t stream) {
  const float* xyz    = (const float*)d_in[0];
  const float* points = (const float*)d_in[1];
  const float* w1     = (const float*)d_in[2];
  const float* w2     = (const float*)d_in[3];
  const float* w3     = (const float*)d_in[4];
  const float* wn_w1  = (const float*)d_in[5];
  const float* wn_b1  = (const float*)d_in[6];
  const float* wn_w2  = (const float*)d_in[7];
  const float* wn_b2  = (const float*)d_in[8];
  const float* wn_w3  = (const float*)d_in[9];
  const float* wn_b3  = (const float*)d_in[10];
  const float* wlin   = (const float*)d_in[11];
  float* out = (float*)d_out;
  char* ws = (char*)d_ws;
  // ws layout (needs ~102 MB)
  int*            knn  = (int*)(ws + 0);                                  // 2 MB
  float4*         xyzw = (float4*)(ws + (2ull  << 20));                   // 1 MB
  float*          pc1  = (float*)(ws + (3ull  << 20));                    // 32 MB
  unsigned short* w2b  = (unsigned short*)(ws + (35ull << 20));           // 32 KB
  unsigned short* w3b  = (unsigned short*)(ws + (35ull << 20) + (1ull << 16)); // 64 KB
  unsigned short* wlb  = (unsigned short*)(ws + (36ull << 20));           // 1 MB
  unsigned short* aggb = (unsigned short*)(ws + (38ull << 20));           // 64 MB

  hipLaunchKernelGGL(pc_prep, dim3(256), dim3(256), 0, stream, xyz, out, xyzw);
  hipLaunchKernelGGL(pc_cast, dim3(2048), dim3(256), 0, stream, w2, w3, wlin, w2b, w3b, wlb);
  hipLaunchKernelGGL(pc_knn, dim3(4096), dim3(256), 0, stream, xyz, (const float4*)xyzw, knn);
  hipLaunchKernelGGL(pc_pc1, dim3(1024), dim3(256), 0, stream, points, w1, pc1);
  hipLaunchKernelGGL(pc_main, dim3(4096), dim3(256), 0, stream, xyz, knn, pc1, w1,
                     w2b, w3b, wn_w1, wn_b1, wn_w2, wn_b2, wn_w3, wn_b3, aggb);
  hipLaunchKernelGGL(pc_final, dim3(128, 2), dim3(256), 0, stream, aggb, wlb, out + (BB * 3 * SS));
}

// Round 20
// 575.999 us; speedup vs baseline: 1.3026x; 1.1638x over previous
//
#include <hip/hip_runtime.h>
#include <stdint.h>

#define LEAKY 0.1f
#define BB 8
#define NN 8192
#define SS 2048
#define KK 32
#define DD 128
#define M1 128
#define M3 256
#define FF 2048
#define H1S 136   // ushort stride for 128-col LDS rows (+8 pad -> 272B)

typedef __bf16 bf16x8 __attribute__((ext_vector_type(8)));
typedef float f32x4 __attribute__((ext_vector_type(4)));
typedef unsigned short ushort8 __attribute__((ext_vector_type(8)));

__device__ __forceinline__ unsigned short f2bf(float f){
  unsigned u = __float_as_uint(f);
  u += 0x7FFFu + ((u >> 16) & 1u);        // RTNE
  return (unsigned short)(u >> 16);
}
__device__ __forceinline__ float bf2f(unsigned short h){
  return __uint_as_float(((unsigned)h) << 16);
}
__device__ __forceinline__ float lrelu_f(float x){ return x > 0.f ? x : LEAKY * x; }

// ---------------- prep: pack xyzw (x,y,z,|p|^2 f32 rn-chain) + copy new_xyz ----------------
__global__ __launch_bounds__(256) void pc_prep(const float* __restrict__ xyz,
                                               float* __restrict__ out,
                                               float4* __restrict__ xyzw){
  int i = blockIdx.x * 256 + threadIdx.x;      // 0..65535
  int b = i >> 13, n = i & (NN - 1);
  const float* xb = xyz + (size_t)b * 3 * NN;
  float x = xb[n], y = xb[NN + n], z = xb[2 * NN + n];
  float sqn = __fadd_rn(__fadd_rn(__fmul_rn(x, x), __fmul_rn(y, y)), __fmul_rn(z, z));
  xyzw[i] = make_float4(x, y, z, sqn);
  if (n < SS) {
    out[(b * 3 + 0) * SS + n] = x;
    out[(b * 3 + 1) * SS + n] = y;
    out[(b * 3 + 2) * SS + n] = z;
  }
}

// ---------------- weight casts to bf16 ----------------
__global__ __launch_bounds__(256) void pc_cast(const float* __restrict__ w2,
                                               const float* __restrict__ w3,
                                               const float* __restrict__ wl,
                                               unsigned short* __restrict__ w2b,
                                               unsigned short* __restrict__ w3b,
                                               unsigned short* __restrict__ wlb){
  int i = blockIdx.x * 256 + threadIdx.x;      // grid covers 524288 = 256*2048 (wlin)
  if (i < M1 * DD) w2b[i] = f2bf(w2[i]);
  if (i < M3 * M1) w3b[i] = f2bf(w3[i]);
  wlb[i] = f2bf(wl[i]);
}

// ---------------- exact KNN: 4 queries/block (wave=query), L1-shared scans ----------------
#define HB 512
#define HSH 19
#define KBASE 0xB7800000u   // sortable(2^-16); 16 bins/octave, covers d^2 in [2^-16, 2^16]
#define BCAP 128
__device__ __forceinline__ unsigned sbin(unsigned k){
  unsigned t = (k >= KBASE) ? ((k - KBASE) >> HSH) : 0u;
  return t > (HB - 1) ? (HB - 1) : t;
}
__device__ __forceinline__ unsigned knn_key(float4 p, float qx, float qy, float qz, float sqs){
  // reference op order: dot = fma(z,qz, fma(y,qy, rn(x*qx))); d = rn(rn(sqs+sqn) - rn(2*dot))
  float dt = fmaf(p.z, qz, fmaf(p.y, qy, __fmul_rn(p.x, qx)));
  float d  = __fsub_rn(__fadd_rn(sqs, p.w), __fmul_rn(2.0f, dt));
  unsigned bits = __float_as_uint(d);
  return bits ^ ((bits & 0x80000000u) ? 0xFFFFFFFFu : 0x80000000u);  // sortable
}

__global__ __launch_bounds__(256, 4) void pc_knn(const float* __restrict__ xyz,
                                                 const float4* __restrict__ xyzw,
                                                 int* __restrict__ knn){
  __shared__ unsigned hist[4][HB];               // 8 KB (wave-private slices)
  __shared__ unsigned long long buf[4][BCAP];    // 4 KB
  __shared__ int outidx[4][KK];                  // 0.5 KB
  const int tid = threadIdx.x;
  const int wave = tid >> 6, lane = tid & 63;
  const int qid = blockIdx.x * 4 + wave;         // grid 4096
  const int b = qid >> 11, s = qid & (SS - 1);
  const unsigned long long lmlt = (1ull << lane) - 1ull;
  const float* xb = xyz + (size_t)b * 3 * NN;
  const float qx = xb[s], qy = xb[NN + s], qz = xb[2 * NN + s];
  const float sqs = __fadd_rn(__fadd_rn(__fmul_rn(qx,qx), __fmul_rn(qy,qy)), __fmul_rn(qz,qz));
  const float4* pb = xyzw + (size_t)b * NN;
  #pragma unroll
  for (int h = 0; h < HB / 64; ++h) hist[wave][h * 64 + lane] = 0;
  __syncthreads();
  // pass 1: histogram; chunked so the block's 4 waves stay phase-locked (L1 reuse)
  for (int c = 0; c < 16; ++c) {
    #pragma unroll
    for (int it = 0; it < 8; ++it) {
      const int i = c * 8 + it;
      atomicAdd(&hist[wave][sbin(knn_key(pb[i * 64 + lane], qx, qy, qz, sqs))], 1u);
    }
    __syncthreads();
  }
  // wave scan over own 512 bins; lane owns bins [lane*8, lane*8+8)
  unsigned lb[8]; unsigned lsum = 0;
  #pragma unroll
  for (int j = 0; j < 8; ++j) { lb[j] = hist[wave][lane * 8 + j]; lsum += lb[j]; }
  unsigned incl = lsum;
  #pragma unroll
  for (int off = 1; off < 64; off <<= 1) {
    unsigned v = __shfl_up(incl, off);
    if (lane >= off) incl += v;
  }
  const unsigned excl = incl - lsum;
  int myT = -1; unsigned mycl = 0;
  if (excl < KK && KK <= excl + lsum) {
    unsigned c = excl;
    #pragma unroll
    for (int j = 0; j < 8; ++j) {
      if (myT < 0) {
        if (c < KK && KK <= c + lb[j]) { myT = lane * 8 + j; mycl = c; }
        else c += lb[j];
      }
    }
  }
  unsigned long long bal = __ballot(myT >= 0);
  const int src = (int)__ffsll(bal) - 1;
  const unsigned uT = (unsigned)__shfl(myT, src);
  const unsigned cl = __shfl(mycl, src);      // count of keys in bins < T (<= 31)
  const unsigned hT = hist[wave][uT];
  const bool useBuf = (hT <= (unsigned)BCAP);
  // pass 2: recompute keys (chunk-locked); bins < T -> outidx (ordered), bin == T -> buf
  int outcnt = 0, bufcnt = 0;
  for (int c = 0; c < 16; ++c) {
    #pragma unroll
    for (int it = 0; it < 8; ++it) {
      const int i = c * 8 + it;
      const unsigned k = knn_key(pb[i * 64 + lane], qx, qy, qz, sqs);
      const unsigned bin = sbin(k);
      const bool less = bin < uT;
      unsigned long long bl = __ballot(less);
      if (less) outidx[wave][outcnt + (int)__popcll(bl & lmlt)] = i * 64 + lane;
      outcnt += (int)__popcll(bl);
      const bool eq = (bin == uT);
      unsigned long long be = __ballot(eq);
      if (useBuf && eq)
        buf[wave][bufcnt + (int)__popcll(be & lmlt)] =
          (((unsigned long long)k) << 32) | (unsigned)(i * 64 + lane);
      bufcnt += (int)__popcll(be);
    }
    __syncthreads();
  }
  const int need = KK - (int)cl;
  if (useBuf) {
    // monotone (key,idx) extraction: buf never modified -> wave-private, no barriers
    unsigned long long last = 0ull;
    for (int t = 0; t < need; ++t) {
      unsigned long long mv = ~0ull;
      for (int j2 = lane; j2 < bufcnt; j2 += 64) {
        unsigned long long v = buf[wave][j2];
        if (v > last && v < mv) mv = v;
      }
      #pragma unroll
      for (int off = 32; off > 0; off >>= 1) {
        unsigned long long ov = __shfl_xor(mv, off);
        if (ov < mv) mv = ov;
      }
      if (lane == 0) outidx[wave][(int)cl + t] = (int)(mv & 0xFFFFFFFFu);
      last = mv;
    }
  } else {
    // rare fallback: monotone extraction by rescanning global
    unsigned long long last = 0ull;
    for (int t = 0; t < need; ++t) {
      unsigned long long mv = ~0ull;
      for (int i = 0; i < 128; ++i) {
        const unsigned k = knn_key(pb[i * 64 + lane], qx, qy, qz, sqs);
        if (sbin(k) == uT) {
          unsigned long long v = (((unsigned long long)k) << 32) | (unsigned)(i * 64 + lane);
          if (v > last && v < mv) mv = v;
        }
      }
      #pragma unroll
      for (int off = 32; off > 0; off >>= 1) {
        unsigned long long ov = __shfl_xor(mv, off);
        if (ov < mv) mv = ov;
      }
      if (lane == 0) outidx[wave][(int)cl + t] = (int)(mv & 0xFFFFFFFFu);
      last = mv;
    }
  }
  __threadfence_block();
  if (lane < KK) knn[(size_t)qid * KK + lane] = outidx[wave][lane];
}

// ---------------- pc1 = points^T @ W1p^T  (fp32), [B*N][128] ----------------
__global__ __launch_bounds__(256) void pc_pc1(const float* __restrict__ points,
                                              const float* __restrict__ w1,
                                              float* __restrict__ pc1){
  int tx = threadIdx.x & 63, ty = threadIdx.x >> 6;
  int m = blockIdx.x * 64 + tx;          // 0..65535
  int og = blockIdx.y * 4 + ty;          // 0..15
  int b = m >> 13, n = m & (NN - 1);
  const float* pbase = points + (size_t)b * DD * NN + n;
  const float* wr = w1 + og * 8 * 131 + 3;
  float acc[8] = {0,0,0,0,0,0,0,0};
  #pragma unroll 4
  for (int c = 0; c < DD; ++c) {
    float pv = pbase[(size_t)c * NN];
    #pragma unroll
    for (int j = 0; j < 8; ++j)
      acc[j] = fmaf(pv, wr[j * 131 + c], acc[j]);
  }
  float* dst = pc1 + (size_t)m * DD + og * 8;
  #pragma unroll
  for (int j = 0; j < 8; ++j) dst[j] = acc[j];
}

// ---------------- in-place 128x128x128 gemm (wave-private rows): hbuf = lrelu(hbuf @ W^T) ----------------
// a-frags loaded per-ks: all LDS reads precede the in-place epilogue writes within the wave.
__device__ __forceinline__ void gemm_tile_ip(unsigned short* hbuf,
                                             const unsigned short* __restrict__ wglb,
                                             int tid){
  const int lane = tid & 63;
  const int r0 = (tid >> 6) * 32;
  const int lr = lane & 15, g = lane >> 4, lkb = g * 8;
  f32x4 acc[2][8] = {};
  #pragma unroll
  for (int ks = 0; ks < 4; ++ks) {
    const int c0 = ks * 32 + lkb;
    bf16x8 a0 = __builtin_bit_cast(bf16x8, *(const ushort8*)(hbuf + (r0 + lr) * H1S + c0));
    bf16x8 a1 = __builtin_bit_cast(bf16x8, *(const ushort8*)(hbuf + (r0 + 16 + lr) * H1S + c0));
    #pragma unroll
    for (int ct = 0; ct < 8; ++ct) {
      bf16x8 bb = __builtin_bit_cast(bf16x8, *(const ushort8*)(wglb + (ct*16 + lr) * DD + c0));
      acc[0][ct] = __builtin_amdgcn_mfma_f32_16x16x32_bf16(a0, bb, acc[0][ct], 0, 0, 0);
      acc[1][ct] = __builtin_amdgcn_mfma_f32_16x16x32_bf16(a1, bb, acc[1][ct], 0, 0, 0);
    }
  }
  #pragma unroll
  for (int rt = 0; rt < 2; ++rt) {
    const int rowb = r0 + rt*16 + g * 4;
    #pragma unroll
    for (int ct = 0; ct < 8; ++ct) {
      const int o = ct*16 + lr;
      #pragma unroll
      for (int e = 0; e < 4; ++e)
        hbuf[(rowb + e) * H1S + o] = f2bf(lrelu_f(acc[rt][ct][e]));
    }
  }
}

// ---------------- gemm3 (one o-half) + in-register agg, c4-outer (low live-set) ----------------
__device__ __forceinline__ void gemm3_agg(const unsigned short* hbuf,
                                          const unsigned short* __restrict__ w3half,
                                          const float* wgtq,
                                          unsigned short* __restrict__ aggb,
                                          int lane, int r0, int rowbase_q, int oh){
  const int lr = lane & 15, g = lane >> 4;
  #pragma unroll
  for (int ch = 0; ch < 2; ++ch) {
    f32x4 acc[2][4] = {};
    #pragma unroll
    for (int ks = 0; ks < 4; ++ks) {
      const int c0 = ks * 32 + g * 8;
      bf16x8 a0 = __builtin_bit_cast(bf16x8, *(const ushort8*)(hbuf + (r0 + lr) * H1S + c0));
      bf16x8 a1 = __builtin_bit_cast(bf16x8, *(const ushort8*)(hbuf + (r0 + 16 + lr) * H1S + c0));
      #pragma unroll
      for (int c4 = 0; c4 < 4; ++c4) {
        const int ct = ch * 4 + c4;
        bf16x8 bb = __builtin_bit_cast(bf16x8, *(const ushort8*)(w3half + (ct*16 + lr) * DD + c0));
        acc[0][c4] = __builtin_amdgcn_mfma_f32_16x16x32_bf16(a0, bb, acc[0][c4], 0, 0, 0);
        acc[1][c4] = __builtin_amdgcn_mfma_f32_16x16x32_bf16(a1, bb, acc[1][c4], 0, 0, 0);
      }
    }
    #pragma unroll
    for (int c4 = 0; c4 < 4; ++c4) {
      float accw[8] = {};
      #pragma unroll
      for (int rt = 0; rt < 2; ++rt) {
        #pragma unroll
        for (int e = 0; e < 4; ++e) {
          const float4* wr = (const float4*)(wgtq + (rt*16 + g*4 + e) * 8);
          const float4 wa = wr[0], wb = wr[1];
          const float h = lrelu_f(acc[rt][c4][e]);   // layer-3 activation
          accw[0] = fmaf(h, wa.x, accw[0]);
          accw[1] = fmaf(h, wa.y, accw[1]);
          accw[2] = fmaf(h, wa.z, accw[2]);
          accw[3] = fmaf(h, wa.w, accw[3]);
          accw[4] = fmaf(h, wb.x, accw[4]);
          accw[5] = fmaf(h, wb.y, accw[5]);
          accw[6] = fmaf(h, wb.z, accw[6]);
          accw[7] = fmaf(h, wb.w, accw[7]);
        }
      }
      #pragma unroll
      for (int w = 0; w < 8; ++w) {
        float v = accw[w];
        v += __shfl_xor(v, 16);
        v += __shfl_xor(v, 32);
        accw[w] = v;
      }
      if (g == 0) {
        const int o = (ch * 4 + c4) * 16 + lr;
        ushort8 pk;
        #pragma unroll
        for (int w = 0; w < 8; ++w) pk[w] = f2bf(accw[w]);
        *(ushort8*)(aggb + (size_t)rowbase_q * FF + oh * (M1 * 8) + o * 8) = pk;
      }
    }
  }
}

// ---------------- fused main: 4 queries, 256 thr, wave-private chain, 1 barrier ----------------
__global__ __launch_bounds__(256, 3) void pc_main(const float* __restrict__ xyz,
    const int* __restrict__ knn, const float* __restrict__ pc1,
    const float* __restrict__ w1,
    const unsigned short* __restrict__ w2b, const unsigned short* __restrict__ w3b,
    const float* __restrict__ wn_w1, const float* __restrict__ wn_b1,
    const float* __restrict__ wn_w2, const float* __restrict__ wn_b2,
    const float* __restrict__ wn_w3, const float* __restrict__ wn_b3,
    unsigned short* __restrict__ aggb){
  __shared__ __align__(16) unsigned short hbuf[128 * H1S];   // 34816 B
  __shared__ __align__(16) float wgtF[4 * 32 * 8];           // 4096 B
  __shared__ float w1d[M1 * 3];                              // 1536 B  -> 40448 B total
  const int tid = threadIdx.x;
  const int wave = tid >> 6, lane = tid & 63;
  const int blk = blockIdx.x;          // 0..4095
  const int b = blk >> 9;
  const int s0 = (blk & 511) * 4;
  const float* xb = xyz + (size_t)b * 3 * NN;
  if (tid < M1) {
    w1d[tid*3+0] = w1[tid*131+0];
    w1d[tid*3+1] = w1[tid*131+1];
    w1d[tid*3+2] = w1[tid*131+2];
  }
  // wave-private: wave = query q; 2 threads per neighbor row
  const int q = wave, k = lane & 31, t2 = lane >> 5;
  const int s = s0 + q;
  const int j = knn[(size_t)(b * SS + s) * KK + k];
  const float dx = xb[j] - xb[s];
  const float dy = xb[NN + j] - xb[NN + s];
  const float dz = xb[2*NN + j] - xb[2*NN + s];
  if (t2 == 0) {
    // weight-net for row k -> wgtF[q][k][0..7] (f32)
    float t0[8], t1[8], t2v[8];
    #pragma unroll
    for (int o = 0; o < 8; ++o)
      t0[o] = fmaxf(fmaf(dz, wn_w1[o*3+2], fmaf(dy, wn_w1[o*3+1], fmaf(dx, wn_w1[o*3+0], wn_b1[o]))), 0.f);
    #pragma unroll
    for (int o = 0; o < 8; ++o) {
      float a = wn_b2[o];
      #pragma unroll
      for (int i2 = 0; i2 < 8; ++i2) a = fmaf(t0[i2], wn_w2[o*8+i2], a);
      t1[o] = fmaxf(a, 0.f);
    }
    #pragma unroll
    for (int o = 0; o < 8; ++o) {
      float a = wn_b3[o];
      #pragma unroll
      for (int i2 = 0; i2 < 8; ++i2) a = fmaf(t1[i2], wn_w3[o*8+i2], a);
      t2v[o] = fmaxf(a, 0.f);
    }
    float* wdst = wgtF + (q * 32 + k) * 8;
    *(float4*)(wdst + 0) = make_float4(t2v[0], t2v[1], t2v[2], t2v[3]);
    *(float4*)(wdst + 4) = make_float4(t2v[4], t2v[5], t2v[6], t2v[7]);
  }
  __syncthreads();   // w1d ready (wgtF/hbuf deps are intra-wave from here on)
  // h1: row q*32+k, cols t2*64..t2*64+63 (16 float4 gather per thread)
  {
    const float4* pcrow = (const float4*)(pc1 + (size_t)(b * NN + j) * DD) + t2 * 16;
    unsigned short* hrow = hbuf + (q * 32 + k) * H1S + t2 * 64;
    #pragma unroll
    for (int o8 = 0; o8 < 8; ++o8) {
      float4 p0 = pcrow[o8*2], p1 = pcrow[o8*2+1];
      float vv[8] = {p0.x, p0.y, p0.z, p0.w, p1.x, p1.y, p1.z, p1.w};
      ushort8 pk;
      #pragma unroll
      for (int e = 0; e < 8; ++e) {
        const int o = t2*64 + o8*8 + e;
        float v = vv[e] + fmaf(dz, w1d[o*3+2], fmaf(dy, w1d[o*3+1], __fmul_rn(dx, w1d[o*3+0])));
        pk[e] = f2bf(lrelu_f(v));
      }
      *(ushort8*)(hrow + o8*8) = pk;
    }
  }
  // no barrier: rows 32q..32q+31 are written and read only by this wave
  gemm_tile_ip(hbuf, w2b, tid);                   // layer 2 (in-place)
  const int rowbase_q = b * SS + s0 + q;
  const float* wgtq = wgtF + q * 256;
  gemm3_agg(hbuf, w3b,            wgtq, aggb, lane, wave * 32, rowbase_q, 0);
  gemm3_agg(hbuf, w3b + 128 * DD, wgtq, aggb, lane, wave * 32, rowbase_q, 1);
}

// ---------------- final: out[b][o][s] = lrelu(agg[bs][:] . wlin[o][:]) ----------------
#define FSTR 72
__global__ __launch_bounds__(256) void pc_final(const unsigned short* __restrict__ aggb,
                                                const unsigned short* __restrict__ wlb,
                                                float* __restrict__ outp){
  __shared__ __align__(16) unsigned short At[128 * FSTR];
  __shared__ __align__(16) unsigned short Bt[128 * FSTR];
  const int tid = threadIdx.x;
  const int mb = blockIdx.x;      // 0..127
  const int nb = blockIdx.y;      // 0..1
  const int lane = tid & 63, wv = tid >> 6;
  const int wm = (wv & 1) * 64, wn = (wv >> 1) * 64;
  const int lr = lane & 15, lkb = (lane >> 4) * 8;
  f32x4 acc[4][4] = {};
  for (int kt = 0; kt < FF / 64; ++kt) {
    #pragma unroll
    for (int it = 0; it < 4; ++it) {
      int seg = it * 256 + tid;
      int row = seg >> 3, c16 = seg & 7;
      *(ushort8*)(At + row * FSTR + c16 * 8) =
        *(const ushort8*)(aggb + (size_t)(mb * 128 + row) * FF + kt * 64 + c16 * 8);
      *(ushort8*)(Bt + row * FSTR + c16 * 8) =
        *(const ushort8*)(wlb + (size_t)(nb * 128 + row) * FF + kt * 64 + c16 * 8);
    }
    __syncthreads();
    #pragma unroll
    for (int ks = 0; ks < 2; ++ks) {
      const int c0 = ks * 32 + lkb;
      bf16x8 a[4], bb[4];
      #pragma unroll
      for (int rt = 0; rt < 4; ++rt)
        a[rt] = __builtin_bit_cast(bf16x8, *(const ushort8*)(At + (wm + rt*16 + lr) * FSTR + c0));
      #pragma unroll
      for (int ct = 0; ct < 4; ++ct)
        bb[ct] = __builtin_bit_cast(bf16x8, *(const ushort8*)(Bt + (wn + ct*16 + lr) * FSTR + c0));
      #pragma unroll
      for (int rt = 0; rt < 4; ++rt)
        #pragma unroll
        for (int ct = 0; ct < 4; ++ct)
          acc[rt][ct] = __builtin_amdgcn_mfma_f32_16x16x32_bf16(a[rt], bb[ct], acc[rt][ct], 0,0,0);
    }
    __syncthreads();
  }
  #pragma unroll
  for (int rt = 0; rt < 4; ++rt) {
    const int r0 = mb * 128 + wm + rt * 16 + (lane >> 4) * 4;
    const int bq = r0 >> 11;
    const int sq = r0 & (SS - 1);
    #pragma unroll
    for (int ct = 0; ct < 4; ++ct) {
      const int o = nb * 128 + wn + ct * 16 + lr;
      float4 vvv = make_float4(lrelu_f(acc[rt][ct][0]), lrelu_f(acc[rt][ct][1]),
                               lrelu_f(acc[rt][ct][2]), lrelu_f(acc[rt][ct][3]));
      *(float4*)(outp + (size_t)bq * M3 * SS + (size_t)o * SS + sq) = vvv;
    }
  }
}

extern "C" void kernel_launch(void* const* d_in, const int* in_sizes, int n_in,
                              void* d_out, int out_size, void* d_ws, size_t ws_size,
                              hipStream_t stream) {
  const float* xyz    = (const float*)d_in[0];
  const float* points = (const float*)d_in[1];
  const float* w1     = (const float*)d_in[2];
  const float* w2     = (const float*)d_in[3];
  const float* w3     = (const float*)d_in[4];
  const float* wn_w1  = (const float*)d_in[5];
  const float* wn_b1  = (const float*)d_in[6];
  const float* wn_w2  = (const float*)d_in[7];
  const float* wn_b2  = (const float*)d_in[8];
  const float* wn_w3  = (const float*)d_in[9];
  const float* wn_b3  = (const float*)d_in[10];
  const float* wlin   = (const float*)d_in[11];
  float* out = (float*)d_out;
  char* ws = (char*)d_ws;
  // ws layout (needs ~102 MB)
  int*            knn  = (int*)(ws + 0);                                  // 2 MB
  float4*         xyzw = (float4*)(ws + (2ull  << 20));                   // 1 MB
  float*          pc1  = (float*)(ws + (3ull  << 20));                    // 32 MB
  unsigned short* w2b  = (unsigned short*)(ws + (35ull << 20));           // 32 KB
  unsigned short* w3b  = (unsigned short*)(ws + (35ull << 20) + (1ull << 16)); // 64 KB
  unsigned short* wlb  = (unsigned short*)(ws + (36ull << 20));           // 1 MB
  unsigned short* aggb = (unsigned short*)(ws + (38ull << 20));           // 64 MB

  hipLaunchKernelGGL(pc_prep, dim3(256), dim3(256), 0, stream, xyz, out, xyzw);
  hipLaunchKernelGGL(pc_cast, dim3(2048), dim3(256), 0, stream, w2, w3, wlin, w2b, w3b, wlb);
  hipLaunchKernelGGL(pc_knn, dim3(4096), dim3(256), 0, stream, xyz, (const float4*)xyzw, knn);
  hipLaunchKernelGGL(pc_pc1, dim3(1024, 4), dim3(256), 0, stream, points, w1, pc1);
  hipLaunchKernelGGL(pc_main, dim3(4096), dim3(256), 0, stream, xyz, knn, pc1, w1,
                     w2b, w3b, wn_w1, wn_b1, wn_w2, wn_b2, wn_w3, wn_b3, aggb);
  hipLaunchKernelGGL(pc_final, dim3(128, 2), dim3(256), 0, stream, aggb, wlb, out + (BB * 3 * SS));
}